// Round 28
// baseline (235.694 us; speedup 1.0000x reference)
//
#include <hip/hip_runtime.h>
#include <hip/hip_bf16.h>
#include <math.h>

#define W_ 1024
#define F_ 512
#define C_ 8
#define B_ 2
#define DH_ 64

typedef __attribute__((ext_vector_type(8))) short short8;
typedef __attribute__((ext_vector_type(4))) short short4v;
typedef __attribute__((ext_vector_type(4))) float f32x4;

__device__ inline unsigned short f2bf(float x) {   // RTNE f32->bf16
    union { float f; unsigned u; } v; v.f = x;
    unsigned r = v.u + 0x7fff + ((v.u >> 16) & 1);
    return (unsigned short)(r >> 16);
}
__device__ inline float bf2f(unsigned short x) {
    union { unsigned u; float f; } v; v.u = (unsigned)x << 16; return v.f;
}

// async global->LDS, 16B per lane; LDS dest = wave-uniform base + lane*16 (global src per-lane OK)
__device__ inline void gll16(const void* g, void* l) {
    __builtin_amdgcn_global_load_lds(
        (const __attribute__((address_space(1))) unsigned int*)g,
        (__attribute__((address_space(3))) unsigned int*)l, 16, 0, 0);
}

// ---------------- RoPE cos/sin table ----------------
__global__ __launch_bounds__(256) void rope_table_kernel(float* __restrict__ cost,
                                                         float* __restrict__ sint) {
    int idx = blockIdx.x * 256 + threadIdx.x;
    if (idx >= W_ * 32) return;
    int w = idx >> 5, i = idx & 31;
    double freq = pow(10000.0, -(double)(2 * i) / 64.0);
    double ang = (double)w * freq;
    cost[idx] = (float)cos(ang);
    sint[idx] = (float)sin(ang);
}

// ---------------- x -> Xt bf16 transpose ----------------
__global__ __launch_bounds__(256) void xt_kernel(
    const float* __restrict__ In, unsigned short* __restrict__ Out)
{
    const int wt = blockIdx.x;
    const int gc = blockIdx.y;
    const int bc = blockIdx.z;
    __shared__ unsigned short T[128][72];
    const int t = threadIdx.x;
    const float* src = In + (size_t)bc * F_ * W_ + (size_t)gc * 64 * W_ + wt * 128;
    const int d0 = (t >> 4) * 4;
    const int w0 = (t & 15) * 4;
    #pragma unroll
    for (int it = 0; it < 2; ++it) {
        int wbase = w0 + it * 64;
        float4 row[4];
        #pragma unroll
        for (int k = 0; k < 4; ++k)
            row[k] = *(const float4*)(src + (size_t)(d0 + k) * W_ + wbase);
        #pragma unroll
        for (int wp = 0; wp < 4; ++wp) {
            ushort4 p;
            p.x = f2bf(((const float*)&row[0])[wp]);
            p.y = f2bf(((const float*)&row[1])[wp]);
            p.z = f2bf(((const float*)&row[2])[wp]);
            p.w = f2bf(((const float*)&row[3])[wp]);
            *(ushort4*)&T[wbase + wp][d0] = p;
        }
    }
    __syncthreads();
    unsigned short* dst = Out + (size_t)bc * W_ * F_ + (size_t)(wt * 128) * F_ + gc * 64;
    const int w = t >> 1, hf = (t & 1) * 32;
    const unsigned short* sr = &T[w][hf];
    uint4* dr = (uint4*)(dst + (size_t)w * F_ + hf);
    dr[0] = ((const uint4*)sr)[0];
    dr[1] = ((const uint4*)sr)[1];
    dr[2] = ((const uint4*)sr)[2];
    dr[3] = ((const uint4*)sr)[3];
}

// ---------------- MFMA per-channel GEMM core (BF16OUT: packed bf16 epilogue) ----------------
template<int BF16OUT>
__device__ inline void mcl_body(const unsigned short* Ag, const unsigned short* Bg,
                                const float* biasp, float* Cp, unsigned short* CpB,
                                int f0, int w0)
{
    __shared__ unsigned short As_[128 * 64];
    __shared__ unsigned short Bs_[128 * 64];
    __shared__ float scr[4][16 * 17];

    const int t = threadIdx.x;
    const int wid = t >> 6, lane = t & 63;
    const int l15 = lane & 15, l4 = lane >> 4;
    const int wf = wid >> 1, ww = wid & 1;

    const int grow = lane >> 3;
    const int gcol = ((lane & 7) * 16) ^ ((grow & 7) << 4);

    f32x4 acc[4][4];
    #pragma unroll
    for (int mt = 0; mt < 4; ++mt)
        #pragma unroll
        for (int nt = 0; nt < 4; ++nt) acc[mt][nt] = (f32x4){0.f, 0.f, 0.f, 0.f};

    for (int ks = 0; ks < 8; ++ks) {
        const int k0 = ks * 64;
        __syncthreads();
        #pragma unroll
        for (int i = 0; i < 4; ++i) {
            int rbase = wid * 32 + i * 8;
            int row = rbase + grow;
            gll16(Ag + (size_t)(f0 + row) * F_ + k0 + (gcol >> 1), &As_[rbase * 64]);
            gll16(Bg + (size_t)(w0 + row) * F_ + k0 + (gcol >> 1), &Bs_[rbase * 64]);
        }
        __syncthreads();
        #pragma unroll
        for (int kf = 0; kf < 2; ++kf) {
            short8 af[4], bf_[4];
            #pragma unroll
            for (int mt = 0; mt < 4; ++mt) {
                int row = wf * 64 + mt * 16 + l15;
                int off = (kf * 64 + l4 * 16) ^ ((row & 7) << 4);
                af[mt] = *(const short8*)((const char*)As_ + row * 128 + off);
            }
            #pragma unroll
            for (int nt = 0; nt < 4; ++nt) {
                int row = ww * 64 + nt * 16 + l15;
                int off = (kf * 64 + l4 * 16) ^ ((row & 7) << 4);
                bf_[nt] = *(const short8*)((const char*)Bs_ + row * 128 + off);
            }
            #pragma unroll
            for (int mt = 0; mt < 4; ++mt)
                #pragma unroll
                for (int nt = 0; nt < 4; ++nt)
                    acc[mt][nt] = __builtin_amdgcn_mfma_f32_16x16x32_bf16(af[mt], bf_[nt], acc[mt][nt], 0, 0, 0);
        }
    }

    const float* bp = biasp + f0 + wf * 64;
    float bz[4][4];
    #pragma unroll
    for (int mt = 0; mt < 4; ++mt)
        #pragma unroll
        for (int r = 0; r < 4; ++r) bz[mt][r] = bp[mt * 16 + l4 * 4 + r];

    float* sw = scr[wid];
    #pragma unroll
    for (int mt = 0; mt < 4; ++mt)
        #pragma unroll
        for (int nt = 0; nt < 4; ++nt) {
            #pragma unroll
            for (int r = 0; r < 4; ++r)
                sw[(l4 * 4 + r) * 17 + l15] = acc[mt][nt][r] + bz[mt][r];
            float4 o;   // same-wave DS ops are ordered; per-wave scratch
            o.x = sw[l15 * 17 + l4 * 4 + 0];
            o.y = sw[l15 * 17 + l4 * 4 + 1];
            o.z = sw[l15 * 17 + l4 * 4 + 2];
            o.w = sw[l15 * 17 + l4 * 4 + 3];
            size_t off = (size_t)(f0 + wf * 64 + mt * 16 + l15) * W_
                       + w0 + ww * 64 + nt * 16 + l4 * 4;
            if (BF16OUT) {
                ushort4 p;
                p.x = f2bf(o.x); p.y = f2bf(o.y); p.z = f2bf(o.z); p.w = f2bf(o.w);
                *(ushort4*)(CpB + off) = p;
            } else {
                *(float4*)(Cp + off) = o;
            }
        }
}

// merged q/k/v GEMM (bf16 out): z = proj*16 + bc -> 1536 blocks, Xt shared in L2
__global__ __launch_bounds__(256) void mcl_qkv_kernel(
    const unsigned short* __restrict__ Xt,
    const unsigned short* __restrict__ W0, const unsigned short* __restrict__ W1,
    const unsigned short* __restrict__ W2,
    const float* __restrict__ b0, const float* __restrict__ b1, const float* __restrict__ b2,
    unsigned short* __restrict__ Y0, unsigned short* __restrict__ Y1,
    unsigned short* __restrict__ Y2)
{
    const int zz = blockIdx.z;
    const int proj = zz >> 4, bc = zz & 15;
    const int c = bc & 7;
    const unsigned short* Wb = proj == 0 ? W0 : (proj == 1 ? W1 : W2);
    const float* bias = proj == 0 ? b0 : (proj == 1 ? b1 : b2);
    unsigned short* Y = proj == 0 ? Y0 : (proj == 1 ? Y1 : Y2);
    mcl_body<1>(Wb + (size_t)c * F_ * F_, Xt + (size_t)bc * W_ * F_,
                bias + c * F_, nullptr, Y + (size_t)bc * F_ * W_,
                blockIdx.y * 128, blockIdx.x * 128);
}

// single-proj GEMM (o-projection, f32 out)
__global__ __launch_bounds__(256) void mcl_mfma_kernel(
    const unsigned short* __restrict__ Xt, const unsigned short* __restrict__ Wb,
    const float* __restrict__ bias, float* __restrict__ Y)
{
    const int bc = blockIdx.z;
    const int c = bc & 7;
    mcl_body<0>(Wb + (size_t)c * F_ * F_, Xt + (size_t)bc * W_ * F_,
                bias + c * F_, Y + (size_t)bc * F_ * W_, nullptr,
                blockIdx.y * 128, blockIdx.x * 128);
}

// ---------------- w-chunked conv kw=7, all-bf16 I/O (+fused RoPE) ----------------
__global__ __launch_bounds__(256) void convrope_w2_kernel(
    const unsigned short* __restrict__ Aq, const unsigned short* __restrict__ Ak,
    const unsigned short* __restrict__ Av,
    unsigned short* __restrict__ Cq, unsigned short* __restrict__ Ck,
    unsigned short* __restrict__ Vb,
    const float* __restrict__ cwq, const float* __restrict__ cbq,
    const float* __restrict__ cwk, const float* __restrict__ cbk,
    const float* __restrict__ cwv, const float* __restrict__ cbv,
    const float* __restrict__ cost, const float* __restrict__ sint)
{
    const int wc = blockIdx.x;          // 0..3 (w chunk of 256)
    const int fp = blockIdx.y;          // 0..255
    const int proj = blockIdx.z >> 1;   // 0=q 1=k 2=v
    const int b = blockIdx.z & 1;
    const unsigned short* In = proj == 0 ? Aq : (proj == 1 ? Ak : Av);
    unsigned short* Out = proj == 0 ? Cq : (proj == 1 ? Ck : Vb);
    const float* CW = proj == 0 ? cwq : (proj == 1 ? cwk : cwv);
    const float* CB = proj == 0 ? cbq : (proj == 1 ? cbk : cbv);
    const int do_rope = (proj < 2);

    __shared__ unsigned rows[C_][264];   // packed {bf16 fi0 | bf16 fi1 << 16}, w0-3..w0+258
    __shared__ float wT[C_][7][C_];
    const int t = threadIdx.x;
    const int w0 = wc * 256;

    #pragma unroll
    for (int ci = 0; ci < 8; ++ci) {
        const unsigned short* s0 = In + ((size_t)(b * C_ + ci) * F_ + 2 * fp) * W_;
        int gw = w0 + t - 3;
        unsigned v = 0;
        if ((unsigned)gw < (unsigned)W_)
            v = (unsigned)s0[gw] | ((unsigned)s0[W_ + gw] << 16);
        rows[ci][t] = v;
        if (t < 8) {
            int gw2 = w0 + 256 + t - 3;
            unsigned v2 = 0;
            if ((unsigned)gw2 < (unsigned)W_)
                v2 = (unsigned)s0[gw2] | ((unsigned)s0[W_ + gw2] << 16);
            rows[ci][256 + t] = v2;
        }
    }
    for (int idx = t; idx < C_ * C_ * 7; idx += 256) {
        int co = idx & 7; int tmp = idx >> 3; int tt = tmp % 7; int ci = tmp / 7;
        wT[ci][tt][co] = CW[((size_t)co * C_ + ci) * 7 + tt];
    }
    float cb[8];
    #pragma unroll
    for (int co = 0; co < 8; co++) cb[co] = CB[co];
    __syncthreads();

    float acc0[8], acc1[8];
    #pragma unroll
    for (int co = 0; co < 8; ++co) { acc0[co] = cb[co]; acc1[co] = cb[co]; }

    #pragma unroll 1
    for (int ci = 0; ci < 8; ++ci) {
        #pragma unroll
        for (int tt = 0; tt < 7; ++tt) {
            float wv[8];
            *(float4*)(wv)     = *(const float4*)&wT[ci][tt][0];
            *(float4*)(wv + 4) = *(const float4*)&wT[ci][tt][4];
            unsigned pv = rows[ci][t + tt];
            union { unsigned u; float f; } c0, c1;
            c0.u = pv << 16;
            c1.u = pv & 0xffff0000u;
            #pragma unroll
            for (int co = 0; co < 8; ++co) {
                acc0[co] = fmaf(c0.f, wv[co], acc0[co]);
                acc1[co] = fmaf(c1.f, wv[co], acc1[co]);
            }
        }
    }

    const int ip = fp & 31;
    const int w = w0 + t;
    float c_ = 1.f, s_ = 0.f;
    if (do_rope) { c_ = cost[w * 32 + ip]; s_ = sint[w * 32 + ip]; }
    #pragma unroll
    for (int co = 0; co < 8; ++co) {
        float o0 = acc0[co], o1 = acc1[co];
        float r0 = do_rope ? (o0 * c_ - o1 * s_) : o0;
        float r1 = do_rope ? (o1 * c_ + o0 * s_) : o1;
        size_t rowb = ((size_t)(b * C_ + co) * F_ + 2 * fp) * W_;
        Out[rowb + w] = f2bf(r0);
        Out[rowb + W_ + w] = f2bf(r1);
    }
}

// ---------------- fused q+k transpose bf16 [head][64][1024] -> bf16 [head][1024][64] --------
__global__ __launch_bounds__(256) void transpose_qk2_kernel(
    const unsigned short* __restrict__ Cq, const unsigned short* __restrict__ Ck,
    unsigned short* __restrict__ Qt, unsigned short* __restrict__ Kt, float qscale)
{
    const int wt = blockIdx.x;
    const int h = blockIdx.y;
    const int which = blockIdx.z;   // 0=q (scaled), 1=k
    const unsigned short* In = which == 0 ? Cq : Ck;
    unsigned short* Out = which == 0 ? Qt : Kt;
    const float scale = which == 0 ? qscale : 1.0f;

    __shared__ unsigned short T[128][72];
    const int t = threadIdx.x;
    const unsigned short* src = In + (size_t)h * 64 * 1024 + wt * 128;
    const int d0 = (t >> 4) * 4;
    const int w0 = (t & 15) * 4;
    #pragma unroll
    for (int it = 0; it < 2; ++it) {
        int wbase = w0 + it * 64;
        ushort4 row[4];
        #pragma unroll
        for (int k = 0; k < 4; ++k)
            row[k] = *(const ushort4*)(src + (size_t)(d0 + k) * 1024 + wbase);
        #pragma unroll
        for (int wp = 0; wp < 4; ++wp) {
            ushort4 p;
            p.x = f2bf(bf2f(((const unsigned short*)&row[0])[wp]) * scale);
            p.y = f2bf(bf2f(((const unsigned short*)&row[1])[wp]) * scale);
            p.z = f2bf(bf2f(((const unsigned short*)&row[2])[wp]) * scale);
            p.w = f2bf(bf2f(((const unsigned short*)&row[3])[wp]) * scale);
            *(ushort4*)&T[wbase + wp][d0] = p;
        }
    }
    __syncthreads();
    unsigned short* dst = Out + ((size_t)h * 1024 + wt * 128) * 64;
    const int w = t >> 1, hf = (t & 1) * 32;
    const unsigned short* sr = &T[w][hf];
    uint4* dr = (uint4*)(dst + w * 64 + hf);
    dr[0] = ((const uint4*)sr)[0];
    dr[1] = ((const uint4*)sr)[1];
    dr[2] = ((const uint4*)sr)[2];
    dr[3] = ((const uint4*)sr)[3];
}

// ---------------- merged weight f32 -> bf16 convert (4 arrays, one dispatch) ----------------
__global__ __launch_bounds__(256) void wcvt4_kernel(
    const float* __restrict__ S0, const float* __restrict__ S1,
    const float* __restrict__ S2, const float* __restrict__ S3,
    unsigned short* __restrict__ D0, unsigned short* __restrict__ D1,
    unsigned short* __restrict__ D2, unsigned short* __restrict__ D3)
{
    const int a = blockIdx.y;
    const float* In = a == 0 ? S0 : (a == 1 ? S1 : (a == 2 ? S2 : S3));
    unsigned short* Out = a == 0 ? D0 : (a == 1 ? D1 : (a == 2 ? D2 : D3));
    size_t i = ((size_t)blockIdx.x * 256 + threadIdx.x) * 8;
    float4 va = *(const float4*)(In + i);
    float4 vb = *(const float4*)(In + i + 4);
    ushort4 pa, pb;
    pa.x = f2bf(va.x); pa.y = f2bf(va.y); pa.z = f2bf(va.z); pa.w = f2bf(va.w);
    pb.x = f2bf(vb.x); pb.y = f2bf(vb.y); pb.z = f2bf(vb.z); pb.w = f2bf(vb.w);
    *(ushort4*)(Out + i) = pa;
    *(ushort4*)(Out + i + 4) = pb;
}

// ---------------- MFMA flash attention (r19-proven form + T5 setprio on PV cluster) ---------
__global__ __launch_bounds__(256) void attn_mfma_kernel(
    const unsigned short* __restrict__ Qt, const unsigned short* __restrict__ Kt,
    const unsigned short* __restrict__ Vb, unsigned short* __restrict__ Ot)
{
    const int head = blockIdx.x;
    const int qt = blockIdx.y;        // 0..3
    const int t = threadIdx.x;
    const int wid = t >> 6;
    const int lane = t & 63;
    const int l15 = lane & 15;
    const int l4 = lane >> 4;

    __shared__ unsigned short Ks[64 * 64];   // 8KB, chunk-swizzled
    __shared__ unsigned short Vs[64 * 64];   // 8KB, chunk-swizzled
    __shared__ char plds_[4][11264];         // per-wave: P [64][88] bf16 / O-pass [16][68] f32
    unsigned short* plds = (unsigned short*)plds_[wid];
    float* olds = (float*)plds_[wid];

    const int q0 = qt * 256 + wid * 64;
    const unsigned short* qb = Qt + ((size_t)head * 1024 + q0) * 64;
    const unsigned short* kb = Kt + (size_t)head * 1024 * 64;
    const unsigned short* vb = Vb + (size_t)head * 64 * 1024;

    short8 aq[4][2];
    #pragma unroll
    for (int mt = 0; mt < 4; ++mt)
        #pragma unroll
        for (int kf = 0; kf < 2; ++kf)
            aq[mt][kf] = *(const short8*)(qb + (size_t)(mt * 16 + l15) * 64 + kf * 32 + l4 * 8);

    const int srow = lane >> 3;
    const int schunk = lane & 7;

    f32x4 oa[4][4];
    float li[4] = {0.f, 0.f, 0.f, 0.f};
    #pragma unroll
    for (int mt = 0; mt < 4; ++mt)
        #pragma unroll
        for (int dt = 0; dt < 4; ++dt) oa[mt][dt] = (f32x4){0.f, 0.f, 0.f, 0.f};

    for (int jt = 0; jt < 16; ++jt) {
        const int j0 = jt * 64;
        __syncthreads();
        #pragma unroll
        for (int i = 0; i < 2; ++i) {
            int rbase = wid * 16 + i * 8;
            int row = rbase + srow;
            gll16(kb + (size_t)(j0 + row) * 64 + ((schunk ^ (row & 7)) * 8), &Ks[rbase * 64]);
            gll16(vb + (size_t)row * 1024 + j0 + ((schunk ^ (row & 7)) * 8), &Vs[rbase * 64]);
        }
        __syncthreads();

        #pragma unroll
        for (int nt = 0; nt < 4; ++nt) {
            int row = nt * 16 + l15;
            short8 bk0 = *(const short8*)&Ks[row * 64 + ((l4 ^ (row & 7)) * 8)];
            short8 bk1 = *(const short8*)&Ks[row * 64 + (((4 + l4) ^ (row & 7)) * 8)];
            #pragma unroll
            for (int mt = 0; mt < 4; ++mt) {
                f32x4 a0 = (f32x4){0.f, 0.f, 0.f, 0.f};
                a0 = __builtin_amdgcn_mfma_f32_16x16x32_bf16(bk0, aq[mt][0], a0, 0, 0, 0);
                a0 = __builtin_amdgcn_mfma_f32_16x16x32_bf16(bk1, aq[mt][1], a0, 0, 0, 0);
                float p0 = __builtin_exp2f(a0[0]);
                float p1 = __builtin_exp2f(a0[1]);
                float p2 = __builtin_exp2f(a0[2]);
                float p3 = __builtin_exp2f(a0[3]);
                li[mt] += (p0 + p1) + (p2 + p3);
                union { __hip_bfloat162 h2[2]; short4v s4; } pk;
                pk.h2[0] = __float22bfloat162_rn(make_float2(p0, p1));
                pk.h2[1] = __float22bfloat162_rn(make_float2(p2, p3));
                *(short4v*)(plds + (size_t)(mt * 16 + l15) * 88 + nt * 16 + l4 * 4) = pk.s4;
            }
        }
        short8 pa[4][2];
        #pragma unroll
        for (int mt = 0; mt < 4; ++mt)
            #pragma unroll
            for (int kf = 0; kf < 2; ++kf)
                pa[mt][kf] = *(const short8*)(plds + (size_t)(mt * 16 + l15) * 88 + kf * 32 + l4 * 8);
        __builtin_amdgcn_s_setprio(1);   // T5: favor this wave through the PV MFMA cluster
        #pragma unroll
        for (int dt = 0; dt < 4; ++dt) {
            int row = dt * 16 + l15;
            short8 bv0 = *(const short8*)&Vs[row * 64 + ((l4 ^ (row & 7)) * 8)];
            short8 bv1 = *(const short8*)&Vs[row * 64 + (((4 + l4) ^ (row & 7)) * 8)];
            #pragma unroll
            for (int mt = 0; mt < 4; ++mt) {
                oa[mt][dt] = __builtin_amdgcn_mfma_f32_16x16x32_bf16(pa[mt][0], bv0, oa[mt][dt], 0, 0, 0);
                oa[mt][dt] = __builtin_amdgcn_mfma_f32_16x16x32_bf16(pa[mt][1], bv1, oa[mt][dt], 0, 0, 0);
            }
        }
        __builtin_amdgcn_s_setprio(0);
    }

    float invq[4][4];
    #pragma unroll
    for (int mt = 0; mt < 4; ++mt) {
        float l = li[mt];
        l += __shfl_xor(l, 16);
        l += __shfl_xor(l, 32);
        float inv = 1.f / l;
        #pragma unroll
        for (int r = 0; r < 4; ++r)
            invq[mt][r] = __shfl(inv, l4 * 4 + r);
    }

    #pragma unroll
    for (int mt = 0; mt < 4; ++mt) {
        #pragma unroll
        for (int dt = 0; dt < 4; ++dt)
            #pragma unroll
            for (int r = 0; r < 4; ++r)
                olds[(size_t)(l4 * 4 + r) * 68 + dt * 16 + l15] = oa[mt][dt][r] * invq[mt][r];
        const int ql = lane >> 2, hf = (lane & 3) * 16;
        const float* srow_ = olds + (size_t)ql * 68 + hf;
        unsigned short* dst = Ot + ((size_t)(head >> 3) * W_ + q0 + mt * 16 + ql) * F_
                                 + (head & 7) * 64 + hf;
        short8 pk0, pk1;
        #pragma unroll
        for (int e = 0; e < 8; ++e) { pk0[e] = (short)f2bf(srow_[e]); pk1[e] = (short)f2bf(srow_[8 + e]); }
        *(short8*)(dst) = pk0;
        *(short8*)(dst + 8) = pk1;
    }
}

// ---------------- 1x1 output conv across channels (f32 in, f32 out) ----------------
__global__ __launch_bounds__(256) void oconv_kernel(
    const float* __restrict__ In, const float* __restrict__ OW,
    const float* __restrict__ OB, float* __restrict__ Out)
{
    size_t idx = (size_t)blockIdx.x * 256 + threadIdx.x;
    int b = (int)(idx >> 19);
    size_t fw = idx & (((size_t)1 << 19) - 1);
    const float* in = In + (size_t)b * C_ * F_ * W_ + fw;
    float* out = Out + (size_t)b * C_ * F_ * W_ + fw;
    float v[8];
    #pragma unroll
    for (int ci = 0; ci < 8; ci++) v[ci] = in[(size_t)ci * F_ * W_];
    #pragma unroll
    for (int co = 0; co < 8; co++) {
        float acc = OB[co];
        #pragma unroll
        for (int ci = 0; ci < 8; ci++) acc = fmaf(v[ci], OW[co * 8 + ci], acc);
        out[(size_t)co * F_ * W_] = acc;
    }
}

extern "C" void kernel_launch(void* const* d_in, const int* in_sizes, int n_in,
                              void* d_out, int out_size, void* d_ws, size_t ws_size,
                              hipStream_t stream) {
    const float* x   = (const float*)d_in[0];
    const float* Wq  = (const float*)d_in[1];
    const float* bq  = (const float*)d_in[2];
    const float* qcw = (const float*)d_in[3];
    const float* qcb = (const float*)d_in[4];
    const float* Wk  = (const float*)d_in[5];
    const float* bk  = (const float*)d_in[6];
    const float* kcw = (const float*)d_in[7];
    const float* kcb = (const float*)d_in[8];
    const float* Wv  = (const float*)d_in[9];
    const float* bv  = (const float*)d_in[10];
    const float* vcw = (const float*)d_in[11];
    const float* vcb = (const float*)d_in[12];
    const float* Wo  = (const float*)d_in[13];
    const float* bo  = (const float*)d_in[14];
    const float* ocw = (const float*)d_in[15];
    const float* ocb = (const float*)d_in[16];

    float* ws = (float*)d_ws;
    const size_t SZ = (size_t)B_ * C_ * F_ * W_;       // 8388608 elements
    const size_t WSF = (size_t)C_ * F_ * F_ / 2;
    unsigned short* Aq = (unsigned short*)ws;
    unsigned short* Cq = Aq + SZ;
    unsigned short* Ak = (unsigned short*)(ws + SZ);
    unsigned short* Ck = Ak + SZ;
    unsigned short* Av = (unsigned short*)(ws + 2 * SZ);
    unsigned short* XtVb = (unsigned short*)(ws + 3 * SZ);     // Xt then Vb
    unsigned short* WqB = (unsigned short*)(ws + 3 * SZ + SZ / 2);
    unsigned short* WkB = (unsigned short*)(ws + 3 * SZ + SZ / 2 + 2 * WSF);
    unsigned short* WvB = (unsigned short*)(ws + 3 * SZ + SZ / 2 + 4 * WSF);
    unsigned short* WoB = (unsigned short*)(ws + 3 * SZ + SZ / 2 + 6 * WSF);
    unsigned short* Qt  = (unsigned short*)(ws + 2 * SZ);      // R2 (Av dead after conv_v)
    unsigned short* Kt  = Qt + SZ;
    unsigned short* Ot  = (unsigned short*)ws;                 // R0 first half (Aq dead)
    float* Ao = ws + SZ;                                       // R1 f32 (Ak/Ck dead)
    float* cost = ws + 4 * SZ;
    float* sint = cost + (size_t)W_ * 32;

    const float qscale = (float)(1.4426950408889634 / 22.627416997969522);

    rope_table_kernel<<<(W_ * 32 + 255) / 256, 256, 0, stream>>>(cost, sint);
    xt_kernel<<<dim3(8, 8, 16), 256, 0, stream>>>(x, XtVb);
    wcvt4_kernel<<<dim3(1024, 4), 256, 0, stream>>>(Wq, Wk, Wv, Wo, WqB, WkB, WvB, WoB);

    mcl_qkv_kernel<<<dim3(8, 4, 48), 256, 0, stream>>>(
        XtVb, WqB, WkB, WvB, bq, bk, bv, Aq, Ak, Av);

    convrope_w2_kernel<<<dim3(4, F_ / 2, 6), 256, 0, stream>>>(
        Aq, Ak, Av, Cq, Ck, XtVb,
        qcw, qcb, kcw, kcb, vcw, vcb, cost, sint);

    // fused q+k transpose (one dispatch)
    transpose_qk2_kernel<<<dim3(W_ / 128, 128, 2), 256, 0, stream>>>(Cq, Ck, Qt, Kt, qscale);

    // attention: 256 q per block (r19 form + setprio)
    attn_mfma_kernel<<<dim3(128, 4), 256, 0, stream>>>(Qt, Kt, XtVb, Ot);

    // o-projection (f32 out) + 1x1 conv
    mcl_mfma_kernel<<<dim3(8, 4, 16), 256, 0, stream>>>(Ot, WoB, bo, Ao);
    oconv_kernel<<<(B_ * F_ * W_) / 256, 256, 0, stream>>>(Ao, ocw, ocb, (float*)d_out);
}

// Round 29
// 234.356 us; speedup vs baseline: 1.0057x; 1.0057x over previous
//
#include <hip/hip_runtime.h>
#include <hip/hip_bf16.h>
#include <math.h>

#define W_ 1024
#define F_ 512
#define C_ 8
#define B_ 2
#define DH_ 64

typedef __attribute__((ext_vector_type(8))) short short8;
typedef __attribute__((ext_vector_type(4))) short short4v;
typedef __attribute__((ext_vector_type(4))) float f32x4;

__device__ inline unsigned short f2bf(float x) {   // RTNE f32->bf16
    union { float f; unsigned u; } v; v.f = x;
    unsigned r = v.u + 0x7fff + ((v.u >> 16) & 1);
    return (unsigned short)(r >> 16);
}
__device__ inline float bf2f(unsigned short x) {
    union { unsigned u; float f; } v; v.u = (unsigned)x << 16; return v.f;
}

// async global->LDS, 16B per lane; LDS dest = wave-uniform base + lane*16 (global src per-lane OK)
__device__ inline void gll16(const void* g, void* l) {
    __builtin_amdgcn_global_load_lds(
        (const __attribute__((address_space(1))) unsigned int*)g,
        (__attribute__((address_space(3))) unsigned int*)l, 16, 0, 0);
}

// ---------------- RoPE cos/sin table ----------------
__global__ __launch_bounds__(256) void rope_table_kernel(float* __restrict__ cost,
                                                         float* __restrict__ sint) {
    int idx = blockIdx.x * 256 + threadIdx.x;
    if (idx >= W_ * 32) return;
    int w = idx >> 5, i = idx & 31;
    double freq = pow(10000.0, -(double)(2 * i) / 64.0);
    double ang = (double)w * freq;
    cost[idx] = (float)cos(ang);
    sint[idx] = (float)sin(ang);
}

// ---------------- x -> Xt bf16 transpose ----------------
__global__ __launch_bounds__(256) void xt_kernel(
    const float* __restrict__ In, unsigned short* __restrict__ Out)
{
    const int wt = blockIdx.x;
    const int gc = blockIdx.y;
    const int bc = blockIdx.z;
    __shared__ unsigned short T[128][72];
    const int t = threadIdx.x;
    const float* src = In + (size_t)bc * F_ * W_ + (size_t)gc * 64 * W_ + wt * 128;
    const int d0 = (t >> 4) * 4;
    const int w0 = (t & 15) * 4;
    #pragma unroll
    for (int it = 0; it < 2; ++it) {
        int wbase = w0 + it * 64;
        float4 row[4];
        #pragma unroll
        for (int k = 0; k < 4; ++k)
            row[k] = *(const float4*)(src + (size_t)(d0 + k) * W_ + wbase);
        #pragma unroll
        for (int wp = 0; wp < 4; ++wp) {
            ushort4 p;
            p.x = f2bf(((const float*)&row[0])[wp]);
            p.y = f2bf(((const float*)&row[1])[wp]);
            p.z = f2bf(((const float*)&row[2])[wp]);
            p.w = f2bf(((const float*)&row[3])[wp]);
            *(ushort4*)&T[wbase + wp][d0] = p;
        }
    }
    __syncthreads();
    unsigned short* dst = Out + (size_t)bc * W_ * F_ + (size_t)(wt * 128) * F_ + gc * 64;
    const int w = t >> 1, hf = (t & 1) * 32;
    const unsigned short* sr = &T[w][hf];
    uint4* dr = (uint4*)(dst + (size_t)w * F_ + hf);
    dr[0] = ((const uint4*)sr)[0];
    dr[1] = ((const uint4*)sr)[1];
    dr[2] = ((const uint4*)sr)[2];
    dr[3] = ((const uint4*)sr)[3];
}

// ---------------- MFMA per-channel GEMM core (BF16OUT: packed bf16 epilogue) ----------------
template<int BF16OUT>
__device__ inline void mcl_body(const unsigned short* Ag, const unsigned short* Bg,
                                const float* biasp, float* Cp, unsigned short* CpB,
                                int f0, int w0)
{
    __shared__ unsigned short As_[128 * 64];
    __shared__ unsigned short Bs_[128 * 64];
    __shared__ float scr[4][16 * 17];

    const int t = threadIdx.x;
    const int wid = t >> 6, lane = t & 63;
    const int l15 = lane & 15, l4 = lane >> 4;
    const int wf = wid >> 1, ww = wid & 1;

    const int grow = lane >> 3;
    const int gcol = ((lane & 7) * 16) ^ ((grow & 7) << 4);

    f32x4 acc[4][4];
    #pragma unroll
    for (int mt = 0; mt < 4; ++mt)
        #pragma unroll
        for (int nt = 0; nt < 4; ++nt) acc[mt][nt] = (f32x4){0.f, 0.f, 0.f, 0.f};

    for (int ks = 0; ks < 8; ++ks) {
        const int k0 = ks * 64;
        __syncthreads();
        #pragma unroll
        for (int i = 0; i < 4; ++i) {
            int rbase = wid * 32 + i * 8;
            int row = rbase + grow;
            gll16(Ag + (size_t)(f0 + row) * F_ + k0 + (gcol >> 1), &As_[rbase * 64]);
            gll16(Bg + (size_t)(w0 + row) * F_ + k0 + (gcol >> 1), &Bs_[rbase * 64]);
        }
        __syncthreads();
        #pragma unroll
        for (int kf = 0; kf < 2; ++kf) {
            short8 af[4], bf_[4];
            #pragma unroll
            for (int mt = 0; mt < 4; ++mt) {
                int row = wf * 64 + mt * 16 + l15;
                int off = (kf * 64 + l4 * 16) ^ ((row & 7) << 4);
                af[mt] = *(const short8*)((const char*)As_ + row * 128 + off);
            }
            #pragma unroll
            for (int nt = 0; nt < 4; ++nt) {
                int row = ww * 64 + nt * 16 + l15;
                int off = (kf * 64 + l4 * 16) ^ ((row & 7) << 4);
                bf_[nt] = *(const short8*)((const char*)Bs_ + row * 128 + off);
            }
            #pragma unroll
            for (int mt = 0; mt < 4; ++mt)
                #pragma unroll
                for (int nt = 0; nt < 4; ++nt)
                    acc[mt][nt] = __builtin_amdgcn_mfma_f32_16x16x32_bf16(af[mt], bf_[nt], acc[mt][nt], 0, 0, 0);
        }
    }

    const float* bp = biasp + f0 + wf * 64;
    float bz[4][4];
    #pragma unroll
    for (int mt = 0; mt < 4; ++mt)
        #pragma unroll
        for (int r = 0; r < 4; ++r) bz[mt][r] = bp[mt * 16 + l4 * 4 + r];

    float* sw = scr[wid];
    #pragma unroll
    for (int mt = 0; mt < 4; ++mt)
        #pragma unroll
        for (int nt = 0; nt < 4; ++nt) {
            #pragma unroll
            for (int r = 0; r < 4; ++r)
                sw[(l4 * 4 + r) * 17 + l15] = acc[mt][nt][r] + bz[mt][r];
            float4 o;   // same-wave DS ops are ordered; per-wave scratch
            o.x = sw[l15 * 17 + l4 * 4 + 0];
            o.y = sw[l15 * 17 + l4 * 4 + 1];
            o.z = sw[l15 * 17 + l4 * 4 + 2];
            o.w = sw[l15 * 17 + l4 * 4 + 3];
            size_t off = (size_t)(f0 + wf * 64 + mt * 16 + l15) * W_
                       + w0 + ww * 64 + nt * 16 + l4 * 4;
            if (BF16OUT) {
                ushort4 p;
                p.x = f2bf(o.x); p.y = f2bf(o.y); p.z = f2bf(o.z); p.w = f2bf(o.w);
                *(ushort4*)(CpB + off) = p;
            } else {
                *(float4*)(Cp + off) = o;
            }
        }
}

// merged q/k/v GEMM (bf16 out): z = proj*16 + bc -> 1536 blocks, Xt shared in L2
__global__ __launch_bounds__(256) void mcl_qkv_kernel(
    const unsigned short* __restrict__ Xt,
    const unsigned short* __restrict__ W0, const unsigned short* __restrict__ W1,
    const unsigned short* __restrict__ W2,
    const float* __restrict__ b0, const float* __restrict__ b1, const float* __restrict__ b2,
    unsigned short* __restrict__ Y0, unsigned short* __restrict__ Y1,
    unsigned short* __restrict__ Y2)
{
    const int zz = blockIdx.z;
    const int proj = zz >> 4, bc = zz & 15;
    const int c = bc & 7;
    const unsigned short* Wb = proj == 0 ? W0 : (proj == 1 ? W1 : W2);
    const float* bias = proj == 0 ? b0 : (proj == 1 ? b1 : b2);
    unsigned short* Y = proj == 0 ? Y0 : (proj == 1 ? Y1 : Y2);
    mcl_body<1>(Wb + (size_t)c * F_ * F_, Xt + (size_t)bc * W_ * F_,
                bias + c * F_, nullptr, Y + (size_t)bc * F_ * W_,
                blockIdx.y * 128, blockIdx.x * 128);
}

// single-proj GEMM (o-projection, f32 out)
__global__ __launch_bounds__(256) void mcl_mfma_kernel(
    const unsigned short* __restrict__ Xt, const unsigned short* __restrict__ Wb,
    const float* __restrict__ bias, float* __restrict__ Y)
{
    const int bc = blockIdx.z;
    const int c = bc & 7;
    mcl_body<0>(Wb + (size_t)c * F_ * F_, Xt + (size_t)bc * W_ * F_,
                bias + c * F_, Y + (size_t)bc * F_ * W_, nullptr,
                blockIdx.y * 128, blockIdx.x * 128);
}

// ---------------- w-chunked conv kw=7, all-bf16 I/O (+fused RoPE) ----------------
__global__ __launch_bounds__(256) void convrope_w2_kernel(
    const unsigned short* __restrict__ Aq, const unsigned short* __restrict__ Ak,
    const unsigned short* __restrict__ Av,
    unsigned short* __restrict__ Cq, unsigned short* __restrict__ Ck,
    unsigned short* __restrict__ Vb,
    const float* __restrict__ cwq, const float* __restrict__ cbq,
    const float* __restrict__ cwk, const float* __restrict__ cbk,
    const float* __restrict__ cwv, const float* __restrict__ cbv,
    const float* __restrict__ cost, const float* __restrict__ sint)
{
    const int wc = blockIdx.x;          // 0..3 (w chunk of 256)
    const int fp = blockIdx.y;          // 0..255
    const int proj = blockIdx.z >> 1;   // 0=q 1=k 2=v
    const int b = blockIdx.z & 1;
    const unsigned short* In = proj == 0 ? Aq : (proj == 1 ? Ak : Av);
    unsigned short* Out = proj == 0 ? Cq : (proj == 1 ? Ck : Vb);
    const float* CW = proj == 0 ? cwq : (proj == 1 ? cwk : cwv);
    const float* CB = proj == 0 ? cbq : (proj == 1 ? cbk : cbv);
    const int do_rope = (proj < 2);

    __shared__ unsigned rows[C_][264];   // packed {bf16 fi0 | bf16 fi1 << 16}, w0-3..w0+258
    __shared__ float wT[C_][7][C_];
    const int t = threadIdx.x;
    const int w0 = wc * 256;

    #pragma unroll
    for (int ci = 0; ci < 8; ++ci) {
        const unsigned short* s0 = In + ((size_t)(b * C_ + ci) * F_ + 2 * fp) * W_;
        int gw = w0 + t - 3;
        unsigned v = 0;
        if ((unsigned)gw < (unsigned)W_)
            v = (unsigned)s0[gw] | ((unsigned)s0[W_ + gw] << 16);
        rows[ci][t] = v;
        if (t < 8) {
            int gw2 = w0 + 256 + t - 3;
            unsigned v2 = 0;
            if ((unsigned)gw2 < (unsigned)W_)
                v2 = (unsigned)s0[gw2] | ((unsigned)s0[W_ + gw2] << 16);
            rows[ci][256 + t] = v2;
        }
    }
    for (int idx = t; idx < C_ * C_ * 7; idx += 256) {
        int co = idx & 7; int tmp = idx >> 3; int tt = tmp % 7; int ci = tmp / 7;
        wT[ci][tt][co] = CW[((size_t)co * C_ + ci) * 7 + tt];
    }
    float cb[8];
    #pragma unroll
    for (int co = 0; co < 8; co++) cb[co] = CB[co];
    __syncthreads();

    float acc0[8], acc1[8];
    #pragma unroll
    for (int co = 0; co < 8; ++co) { acc0[co] = cb[co]; acc1[co] = cb[co]; }

    #pragma unroll 1
    for (int ci = 0; ci < 8; ++ci) {
        #pragma unroll
        for (int tt = 0; tt < 7; ++tt) {
            float wv[8];
            *(float4*)(wv)     = *(const float4*)&wT[ci][tt][0];
            *(float4*)(wv + 4) = *(const float4*)&wT[ci][tt][4];
            unsigned pv = rows[ci][t + tt];
            union { unsigned u; float f; } c0, c1;
            c0.u = pv << 16;
            c1.u = pv & 0xffff0000u;
            #pragma unroll
            for (int co = 0; co < 8; ++co) {
                acc0[co] = fmaf(c0.f, wv[co], acc0[co]);
                acc1[co] = fmaf(c1.f, wv[co], acc1[co]);
            }
        }
    }

    const int ip = fp & 31;
    const int w = w0 + t;
    float c_ = 1.f, s_ = 0.f;
    if (do_rope) { c_ = cost[w * 32 + ip]; s_ = sint[w * 32 + ip]; }
    #pragma unroll
    for (int co = 0; co < 8; ++co) {
        float o0 = acc0[co], o1 = acc1[co];
        float r0 = do_rope ? (o0 * c_ - o1 * s_) : o0;
        float r1 = do_rope ? (o1 * c_ + o0 * s_) : o1;
        size_t rowb = ((size_t)(b * C_ + co) * F_ + 2 * fp) * W_;
        Out[rowb + w] = f2bf(r0);
        Out[rowb + W_ + w] = f2bf(r1);
    }
}

// ---------------- fused q+k transpose bf16 [head][64][1024] -> bf16 [head][1024][64] --------
__global__ __launch_bounds__(256) void transpose_qk2_kernel(
    const unsigned short* __restrict__ Cq, const unsigned short* __restrict__ Ck,
    unsigned short* __restrict__ Qt, unsigned short* __restrict__ Kt, float qscale)
{
    const int wt = blockIdx.x;
    const int h = blockIdx.y;
    const int which = blockIdx.z;   // 0=q (scaled), 1=k
    const unsigned short* In = which == 0 ? Cq : Ck;
    unsigned short* Out = which == 0 ? Qt : Kt;
    const float scale = which == 0 ? qscale : 1.0f;

    __shared__ unsigned short T[128][72];
    const int t = threadIdx.x;
    const unsigned short* src = In + (size_t)h * 64 * 1024 + wt * 128;
    const int d0 = (t >> 4) * 4;
    const int w0 = (t & 15) * 4;
    #pragma unroll
    for (int it = 0; it < 2; ++it) {
        int wbase = w0 + it * 64;
        ushort4 row[4];
        #pragma unroll
        for (int k = 0; k < 4; ++k)
            row[k] = *(const ushort4*)(src + (size_t)(d0 + k) * 1024 + wbase);
        #pragma unroll
        for (int wp = 0; wp < 4; ++wp) {
            ushort4 p;
            p.x = f2bf(bf2f(((const unsigned short*)&row[0])[wp]) * scale);
            p.y = f2bf(bf2f(((const unsigned short*)&row[1])[wp]) * scale);
            p.z = f2bf(bf2f(((const unsigned short*)&row[2])[wp]) * scale);
            p.w = f2bf(bf2f(((const unsigned short*)&row[3])[wp]) * scale);
            *(ushort4*)&T[wbase + wp][d0] = p;
        }
    }
    __syncthreads();
    unsigned short* dst = Out + ((size_t)h * 1024 + wt * 128) * 64;
    const int w = t >> 1, hf = (t & 1) * 32;
    const unsigned short* sr = &T[w][hf];
    uint4* dr = (uint4*)(dst + w * 64 + hf);
    dr[0] = ((const uint4*)sr)[0];
    dr[1] = ((const uint4*)sr)[1];
    dr[2] = ((const uint4*)sr)[2];
    dr[3] = ((const uint4*)sr)[3];
}

// ---------------- merged weight f32 -> bf16 convert (4 arrays, one dispatch) ----------------
__global__ __launch_bounds__(256) void wcvt4_kernel(
    const float* __restrict__ S0, const float* __restrict__ S1,
    const float* __restrict__ S2, const float* __restrict__ S3,
    unsigned short* __restrict__ D0, unsigned short* __restrict__ D1,
    unsigned short* __restrict__ D2, unsigned short* __restrict__ D3)
{
    const int a = blockIdx.y;
    const float* In = a == 0 ? S0 : (a == 1 ? S1 : (a == 2 ? S2 : S3));
    unsigned short* Out = a == 0 ? D0 : (a == 1 ? D1 : (a == 2 ? D2 : D3));
    size_t i = ((size_t)blockIdx.x * 256 + threadIdx.x) * 8;
    float4 va = *(const float4*)(In + i);
    float4 vb = *(const float4*)(In + i + 4);
    ushort4 pa, pb;
    pa.x = f2bf(va.x); pa.y = f2bf(va.y); pa.z = f2bf(va.z); pa.w = f2bf(va.w);
    pb.x = f2bf(vb.x); pb.y = f2bf(vb.y); pb.z = f2bf(vb.z); pb.w = f2bf(vb.w);
    *(ushort4*)(Out + i) = pa;
    *(ushort4*)(Out + i + 4) = pb;
}

// ---------------- MFMA flash attention (r19-proven form + T5 setprio on PV cluster) ---------
__global__ __launch_bounds__(256) void attn_mfma_kernel(
    const unsigned short* __restrict__ Qt, const unsigned short* __restrict__ Kt,
    const unsigned short* __restrict__ Vb, unsigned short* __restrict__ Ot)
{
    const int head = blockIdx.x;
    const int qt = blockIdx.y;        // 0..3
    const int t = threadIdx.x;
    const int wid = t >> 6;
    const int lane = t & 63;
    const int l15 = lane & 15;
    const int l4 = lane >> 4;

    __shared__ unsigned short Ks[64 * 64];   // 8KB, chunk-swizzled
    __shared__ unsigned short Vs[64 * 64];   // 8KB, chunk-swizzled
    __shared__ char plds_[4][11264];         // per-wave: P [64][88] bf16 / O-pass [16][68] f32
    unsigned short* plds = (unsigned short*)plds_[wid];
    float* olds = (float*)plds_[wid];

    const int q0 = qt * 256 + wid * 64;
    const unsigned short* qb = Qt + ((size_t)head * 1024 + q0) * 64;
    const unsigned short* kb = Kt + (size_t)head * 1024 * 64;
    const unsigned short* vb = Vb + (size_t)head * 64 * 1024;

    short8 aq[4][2];
    #pragma unroll
    for (int mt = 0; mt < 4; ++mt)
        #pragma unroll
        for (int kf = 0; kf < 2; ++kf)
            aq[mt][kf] = *(const short8*)(qb + (size_t)(mt * 16 + l15) * 64 + kf * 32 + l4 * 8);

    const int srow = lane >> 3;
    const int schunk = lane & 7;

    f32x4 oa[4][4];
    float li[4] = {0.f, 0.f, 0.f, 0.f};
    #pragma unroll
    for (int mt = 0; mt < 4; ++mt)
        #pragma unroll
        for (int dt = 0; dt < 4; ++dt) oa[mt][dt] = (f32x4){0.f, 0.f, 0.f, 0.f};

    for (int jt = 0; jt < 16; ++jt) {
        const int j0 = jt * 64;
        __syncthreads();
        #pragma unroll
        for (int i = 0; i < 2; ++i) {
            int rbase = wid * 16 + i * 8;
            int row = rbase + srow;
            gll16(kb + (size_t)(j0 + row) * 64 + ((schunk ^ (row & 7)) * 8), &Ks[rbase * 64]);
            gll16(vb + (size_t)row * 1024 + j0 + ((schunk ^ (row & 7)) * 8), &Vs[rbase * 64]);
        }
        __syncthreads();

        #pragma unroll
        for (int nt = 0; nt < 4; ++nt) {
            int row = nt * 16 + l15;
            short8 bk0 = *(const short8*)&Ks[row * 64 + ((l4 ^ (row & 7)) * 8)];
            short8 bk1 = *(const short8*)&Ks[row * 64 + (((4 + l4) ^ (row & 7)) * 8)];
            #pragma unroll
            for (int mt = 0; mt < 4; ++mt) {
                f32x4 a0 = (f32x4){0.f, 0.f, 0.f, 0.f};
                a0 = __builtin_amdgcn_mfma_f32_16x16x32_bf16(bk0, aq[mt][0], a0, 0, 0, 0);
                a0 = __builtin_amdgcn_mfma_f32_16x16x32_bf16(bk1, aq[mt][1], a0, 0, 0, 0);
                float p0 = __builtin_exp2f(a0[0]);
                float p1 = __builtin_exp2f(a0[1]);
                float p2 = __builtin_exp2f(a0[2]);
                float p3 = __builtin_exp2f(a0[3]);
                li[mt] += (p0 + p1) + (p2 + p3);
                union { __hip_bfloat162 h2[2]; short4v s4; } pk;
                pk.h2[0] = __float22bfloat162_rn(make_float2(p0, p1));
                pk.h2[1] = __float22bfloat162_rn(make_float2(p2, p3));
                *(short4v*)(plds + (size_t)(mt * 16 + l15) * 88 + nt * 16 + l4 * 4) = pk.s4;
            }
        }
        short8 pa[4][2];
        #pragma unroll
        for (int mt = 0; mt < 4; ++mt)
            #pragma unroll
            for (int kf = 0; kf < 2; ++kf)
                pa[mt][kf] = *(const short8*)(plds + (size_t)(mt * 16 + l15) * 88 + kf * 32 + l4 * 8);
        __builtin_amdgcn_s_setprio(1);   // T5: favor this wave through the PV MFMA cluster
        #pragma unroll
        for (int dt = 0; dt < 4; ++dt) {
            int row = dt * 16 + l15;
            short8 bv0 = *(const short8*)&Vs[row * 64 + ((l4 ^ (row & 7)) * 8)];
            short8 bv1 = *(const short8*)&Vs[row * 64 + (((4 + l4) ^ (row & 7)) * 8)];
            #pragma unroll
            for (int mt = 0; mt < 4; ++mt) {
                oa[mt][dt] = __builtin_amdgcn_mfma_f32_16x16x32_bf16(pa[mt][0], bv0, oa[mt][dt], 0, 0, 0);
                oa[mt][dt] = __builtin_amdgcn_mfma_f32_16x16x32_bf16(pa[mt][1], bv1, oa[mt][dt], 0, 0, 0);
            }
        }
        __builtin_amdgcn_s_setprio(0);
    }

    float invq[4][4];
    #pragma unroll
    for (int mt = 0; mt < 4; ++mt) {
        float l = li[mt];
        l += __shfl_xor(l, 16);
        l += __shfl_xor(l, 32);
        float inv = 1.f / l;
        #pragma unroll
        for (int r = 0; r < 4; ++r)
            invq[mt][r] = __shfl(inv, l4 * 4 + r);
    }

    #pragma unroll
    for (int mt = 0; mt < 4; ++mt) {
        #pragma unroll
        for (int dt = 0; dt < 4; ++dt)
            #pragma unroll
            for (int r = 0; r < 4; ++r)
                olds[(size_t)(l4 * 4 + r) * 68 + dt * 16 + l15] = oa[mt][dt][r] * invq[mt][r];
        const int ql = lane >> 2, hf = (lane & 3) * 16;
        const float* srow_ = olds + (size_t)ql * 68 + hf;
        unsigned short* dst = Ot + ((size_t)(head >> 3) * W_ + q0 + mt * 16 + ql) * F_
                                 + (head & 7) * 64 + hf;
        short8 pk0, pk1;
        #pragma unroll
        for (int e = 0; e < 8; ++e) { pk0[e] = (short)f2bf(srow_[e]); pk1[e] = (short)f2bf(srow_[8 + e]); }
        *(short8*)(dst) = pk0;
        *(short8*)(dst + 8) = pk1;
    }
}

// ---------------- 1x1 output conv across channels (f32 in, f32 out) ----------------
__global__ __launch_bounds__(256) void oconv_kernel(
    const float* __restrict__ In, const float* __restrict__ OW,
    const float* __restrict__ OB, float* __restrict__ Out)
{
    size_t idx = (size_t)blockIdx.x * 256 + threadIdx.x;
    int b = (int)(idx >> 19);
    size_t fw = idx & (((size_t)1 << 19) - 1);
    const float* in = In + (size_t)b * C_ * F_ * W_ + fw;
    float* out = Out + (size_t)b * C_ * F_ * W_ + fw;
    float v[8];
    #pragma unroll
    for (int ci = 0; ci < 8; ci++) v[ci] = in[(size_t)ci * F_ * W_];
    #pragma unroll
    for (int co = 0; co < 8; co++) {
        float acc = OB[co];
        #pragma unroll
        for (int ci = 0; ci < 8; ci++) acc = fmaf(v[ci], OW[co * 8 + ci], acc);
        out[(size_t)co * F_ * W_] = acc;
    }
}

extern "C" void kernel_launch(void* const* d_in, const int* in_sizes, int n_in,
                              void* d_out, int out_size, void* d_ws, size_t ws_size,
                              hipStream_t stream) {
    const float* x   = (const float*)d_in[0];
    const float* Wq  = (const float*)d_in[1];
    const float* bq  = (const float*)d_in[2];
    const float* qcw = (const float*)d_in[3];
    const float* qcb = (const float*)d_in[4];
    const float* Wk  = (const float*)d_in[5];
    const float* bk  = (const float*)d_in[6];
    const float* kcw = (const float*)d_in[7];
    const float* kcb = (const float*)d_in[8];
    const float* Wv  = (const float*)d_in[9];
    const float* bv  = (const float*)d_in[10];
    const float* vcw = (const float*)d_in[11];
    const float* vcb = (const float*)d_in[12];
    const float* Wo  = (const float*)d_in[13];
    const float* bo  = (const float*)d_in[14];
    const float* ocw = (const float*)d_in[15];
    const float* ocb = (const float*)d_in[16];

    float* ws = (float*)d_ws;
    const size_t SZ = (size_t)B_ * C_ * F_ * W_;       // 8388608 elements
    const size_t WSF = (size_t)C_ * F_ * F_ / 2;
    unsigned short* Aq = (unsigned short*)ws;
    unsigned short* Cq = Aq + SZ;
    unsigned short* Ak = (unsigned short*)(ws + SZ);
    unsigned short* Ck = Ak + SZ;
    unsigned short* Av = (unsigned short*)(ws + 2 * SZ);
    unsigned short* XtVb = (unsigned short*)(ws + 3 * SZ);     // Xt then Vb
    unsigned short* WqB = (unsigned short*)(ws + 3 * SZ + SZ / 2);
    unsigned short* WkB = (unsigned short*)(ws + 3 * SZ + SZ / 2 + 2 * WSF);
    unsigned short* WvB = (unsigned short*)(ws + 3 * SZ + SZ / 2 + 4 * WSF);
    unsigned short* WoB = (unsigned short*)(ws + 3 * SZ + SZ / 2 + 6 * WSF);
    unsigned short* Qt  = (unsigned short*)(ws + 2 * SZ);      // R2 (Av dead after conv_v)
    unsigned short* Kt  = Qt + SZ;
    unsigned short* Ot  = (unsigned short*)ws;                 // R0 first half (Aq dead)
    float* Ao = ws + SZ;                                       // R1 f32 (Ak/Ck dead)
    float* cost = ws + 4 * SZ;
    float* sint = cost + (size_t)W_ * 32;

    const float qscale = (float)(1.4426950408889634 / 22.627416997969522);

    rope_table_kernel<<<(W_ * 32 + 255) / 256, 256, 0, stream>>>(cost, sint);
    xt_kernel<<<dim3(8, 8, 16), 256, 0, stream>>>(x, XtVb);
    wcvt4_kernel<<<dim3(1024, 4), 256, 0, stream>>>(Wq, Wk, Wv, Wo, WqB, WkB, WvB, WoB);

    mcl_qkv_kernel<<<dim3(8, 4, 48), 256, 0, stream>>>(
        XtVb, WqB, WkB, WvB, bq, bk, bv, Aq, Ak, Av);

    convrope_w2_kernel<<<dim3(4, F_ / 2, 6), 256, 0, stream>>>(
        Aq, Ak, Av, Cq, Ck, XtVb,
        qcw, qcb, kcw, kcb, vcw, vcb, cost, sint);

    // fused q+k transpose (one dispatch)
    transpose_qk2_kernel<<<dim3(W_ / 128, 128, 2), 256, 0, stream>>>(Cq, Ck, Qt, Kt, qscale);

    // attention: 256 q per block (r19 form + setprio)
    attn_mfma_kernel<<<dim3(128, 4), 256, 0, stream>>>(Qt, Kt, XtVb, Ot);

    // o-projection (f32 out) + 1x1 conv
    mcl_mfma_kernel<<<dim3(8, 4, 16), 256, 0, stream>>>(Ot, WoB, bo, Ao);
    oconv_kernel<<<(B_ * F_ * W_) / 256, 256, 0, stream>>>(Ao, ocw, ocb, (float*)d_out);
}